// Round 9
// baseline (591.573 us; speedup 1.0000x reference)
//
#include <hip/hip_runtime.h>
#include <hip/hip_bf16.h>
#include <math.h>

#define IN_CH 128
#define HID 64
#define HEADS 4
#define C1 (HEADS*HID)   // 256
#define OUT_CH 64
#define NPB 128          // nodes per bucket (d>>7)

typedef __attribute__((ext_vector_type(8))) short short8v;
typedef __attribute__((ext_vector_type(4))) float f32x4;

__device__ __forceinline__ float lrelu(float x){ return x > 0.f ? x : 0.2f*x; }

__device__ __forceinline__ ushort f2b(float f){
  unsigned u = __builtin_bit_cast(unsigned, f);
  unsigned r = (u + 0x7FFF + ((u>>16)&1)) >> 16;
  return (ushort)r;
}
__device__ __forceinline__ float b2f(ushort b){
  unsigned u = ((unsigned)b) << 16;
  return __builtin_bit_cast(float, u);
}

__device__ __forceinline__ float wsum64(float v){
  #pragma unroll
  for (int m = 32; m >= 1; m >>= 1) v += __shfl_xor(v, m, 64);
  return v;
}
__device__ __forceinline__ float wmax64(float v){
  #pragma unroll
  for (int m = 32; m >= 1; m >>= 1) v = fmaxf(v, __shfl_xor(v, m, 64));
  return v;
}

__device__ __forceinline__ float dot2(unsigned ua, unsigned ub){
  float la = __builtin_bit_cast(float, ua << 16);
  float ha = __builtin_bit_cast(float, ua & 0xFFFF0000u);
  float lb = __builtin_bit_cast(float, ub << 16);
  float hb = __builtin_bit_cast(float, ub & 0xFFFF0000u);
  return la*lb + ha*hb;
}

// ---------------- CSR build ----------------

__global__ void k_init(int* deg, int n){
  int i = blockIdx.x*256 + threadIdx.x;
  if (i < n) deg[i] = 1;               // self-loop slot
}

__global__ void k_hist(const int* __restrict__ dst, int* deg, int e){
  int i = blockIdx.x*256 + threadIdx.x;
  if (i < e) atomicAdd(&deg[dst[i]], 1);
}

__global__ void k_blocksum(const int* __restrict__ deg, int* bsum, int n){
  __shared__ int buf[256];
  int b = blockIdx.x, tid = threadIdx.x;
  int i = b*256 + tid;
  buf[tid] = (i < n) ? deg[i] : 0;
  __syncthreads();
  for (int off = 128; off > 0; off >>= 1){
    if (tid < off) buf[tid] += buf[tid + off];
    __syncthreads();
  }
  if (tid == 0) bsum[b] = buf[0];
}

__global__ void k_scanb(int* bsum, int nb){
  __shared__ int buf[256];
  int tid = threadIdx.x;
  int v = (tid < nb) ? bsum[tid] : 0;
  buf[tid] = v;
  __syncthreads();
  for (int off = 1; off < 256; off <<= 1){
    int t = (tid >= off) ? buf[tid - off] : 0;
    __syncthreads();
    buf[tid] += t;
    __syncthreads();
  }
  if (tid < nb) bsum[tid] = buf[tid] - v;
}

// rowptr + self-loop slots (last slot of each node)
__global__ void k_scanfinal(const int* __restrict__ deg, const int* __restrict__ bsum,
                            int* rowptr, int* csrc, int n){
  __shared__ int buf[256];
  int b = blockIdx.x, tid = threadIdx.x;
  int i = b*256 + tid;
  int v = (i < n) ? deg[i] : 0;
  buf[tid] = v;
  __syncthreads();
  for (int off = 1; off < 256; off <<= 1){
    int t = (tid >= off) ? buf[tid - off] : 0;
    __syncthreads();
    buf[tid] += t;
    __syncthreads();
  }
  if (i < n){
    int r = bsum[b] + buf[tid];
    rowptr[i + 1] = r;
    csrc[r - 1] = i;                    // self-loop
  }
  if (b == 0 && tid == 0) rowptr[0] = 0;
}

// ebase[b] = edge-only prefix at bucket start; ecnt=0. NB buckets (<=512).
__global__ void k_ebase(const int* __restrict__ rowptr, int* ebase, int* ecnt, int nb, int n){
  int b = threadIdx.x;
  if (b < nb){
    int node = min(n, b*NPB);
    ebase[b] = rowptr[node] - node;
    ecnt[b] = 0;
  }
}

// pass1: bin edges by dst bucket; packed src|(d_local<<17)
__global__ void k_binedges(const int* __restrict__ src, const int* __restrict__ dst,
                           const int* __restrict__ ebase, int* ecnt,
                           unsigned* __restrict__ ebuf, int e){
  int i = blockIdx.x*256 + threadIdx.x;
  if (i < e){
    int d = dst[i];
    int b = d >> 7;
    int p = ebase[b] + atomicAdd(&ecnt[b], 1);
    ebuf[p] = (unsigned)src[i] | ((unsigned)(d & (NPB-1)) << 17);
  }
}

// pass2: one block per bucket, LDS cursors, local csrc writes
__global__ __launch_bounds__(256) void k_fillcsr(
    const unsigned* __restrict__ ebuf, const int* __restrict__ ebase,
    const int* __restrict__ ecnt, const int* __restrict__ rowptr,
    int* __restrict__ csrc, int n)
{
  __shared__ int cur[NPB];
  int b = blockIdx.x, tid = threadIdx.x;
  int base = b*NPB;
  int nn = min(NPB, n - base);
  if (tid < nn) cur[tid] = rowptr[base + tid];
  __syncthreads();
  int es = ebase[b], ec = ecnt[b];
  for (int idx = tid; idx < ec; idx += 256){
    unsigned p = __builtin_nontemporal_load(ebuf + es + idx);
    int s = p & 0x1FFFF;
    int j = p >> 17;
    int slot = atomicAdd(&cur[j], 1);
    csrc[slot] = s;
  }
}

// ---------------- weight folds ----------------

__global__ void k_tw(const float* __restrict__ W, ushort* __restrict__ Wt, int K, int N){
  int i = blockIdx.x*256 + threadIdx.x;
  if (i < K*N){
    int k = i / N, c = i - k*N;
    Wt[(size_t)c*K + k] = f2b(W[i]);
  }
}

// block0: fold1 (512 thr); block1: fold2 (first 256 thr)
__global__ void k_folds(const float* __restrict__ W1, const float* __restrict__ as1v,
                        const float* __restrict__ ad1v, const float* __restrict__ W2,
                        const float* __restrict__ as2v, const float* __restrict__ ad2v,
                        float* was4, float* wad4, float* w2s, float* w2d){
  int tid = threadIdx.x;
  if (blockIdx.x == 0){
    int c = tid >> 2, h = tid & 3;
    float s = 0.f, d = 0.f;
    for (int j = 0; j < HID; ++j){
      float w = W1[c*C1 + h*HID + j];
      s += w * as1v[h*HID + j];
      d += w * ad1v[h*HID + j];
    }
    was4[tid] = s; wad4[tid] = d;
  } else if (tid < 256){
    float s = 0.f, d = 0.f;
    for (int o = 0; o < OUT_CH; ++o){
      float w = W2[tid*OUT_CH + o];
      s += w * as2v[o];
      d += w * ad2v[o];
    }
    w2s[tid] = s; w2d[tid] = d;
  }
}

// fused: cast x->bf16 + conv1 attention scores. wave per node, lane = 2 channels.
__global__ __launch_bounds__(64) void k_fattc(const float* __restrict__ x,
    const float* __restrict__ was4, const float* __restrict__ wad4,
    ushort* __restrict__ xb, float* __restrict__ as1, float* __restrict__ ad1, int n){
  int i = blockIdx.x;
  int l = threadIdx.x;
  float2 u = *(const float2*)(x + (size_t)i*IN_CH + 2*l);
  ushort2 o; o.x = f2b(u.x); o.y = f2b(u.y);
  *(ushort2*)(xb + (size_t)i*IN_CH + 2*l) = o;
  float v0 = u.x, v1 = u.y;
  f32x4 s0 = *(const f32x4*)(was4 + 8*l);
  f32x4 s1 = *(const f32x4*)(was4 + 8*l + 4);
  f32x4 d0 = *(const f32x4*)(wad4 + 8*l);
  f32x4 d1 = *(const f32x4*)(wad4 + 8*l + 4);
  f32x4 ps, pd;
  #pragma unroll
  for (int h = 0; h < 4; ++h){
    ps[h] = wsum64(v0*s0[h] + v1*s1[h]);
    pd[h] = wsum64(v0*d0[h] + v1*d1[h]);
  }
  if (l == 0){
    *(f32x4*)(as1 + 4*i) = ps;
    *(f32x4*)(ad1 + 4*i) = pd;
  }
}

// as2/ad2 from z1: wave per node, lane = 4 channels
__global__ __launch_bounds__(64) void k_fatt2(const ushort* __restrict__ z1b,
    const float* __restrict__ w2s, const float* __restrict__ w2d,
    float* __restrict__ as2, float* __restrict__ ad2, int n){
  int i = blockIdx.x;
  int l = threadIdx.x;
  ushort4 u = *(const ushort4*)(z1b + (size_t)i*C1 + 4*l);
  float v0 = b2f(u.x), v1 = b2f(u.y), v2 = b2f(u.z), v3 = b2f(u.w);
  f32x4 s = *(const f32x4*)(w2s + 4*l);
  f32x4 d = *(const f32x4*)(w2d + 4*l);
  float ps = wsum64(v0*s[0] + v1*s[1] + v2*s[2] + v3*s[3]);
  float pd = wsum64(v0*d[0] + v1*d[1] + v2*d[2] + v3*d[3]);
  if (l == 0){ as2[i] = ps; ad2[i] = pd; }
}

// ---------------- softmax stats + normalized weights ----------------
__global__ __launch_bounds__(64) void k_stats1(
    const float* __restrict__ as1, const float* __restrict__ ad1,
    const int* __restrict__ rowptr, const int* __restrict__ csrc,
    float* __restrict__ wgt, int n)
{
  int i = blockIdx.x;
  int l = threadIdx.x;
  int beg = rowptr[i], end = rowptr[i+1];
  f32x4 ad4 = *(const f32x4*)(ad1 + 4*i);

  f32x4 m = (f32x4)(-1e30f), s = (f32x4)(0.f);
  for (int sl = beg + l; sl < end; sl += 64){
    int sj = csrc[sl];
    f32x4 a4 = *(const f32x4*)(as1 + 4*sj);
    f32x4 al;
    #pragma unroll
    for (int h = 0; h < 4; ++h){
      float a = lrelu(a4[h] + ad4[h]);
      al[h] = a;
      if (a <= m[h]) s[h] += expf(a - m[h]);
      else { s[h] = s[h]*expf(m[h] - a) + 1.f; m[h] = a; }
    }
    *(f32x4*)(wgt + 4*(size_t)sl) = al;
  }
  f32x4 M2, rd;
  #pragma unroll
  for (int h = 0; h < 4; ++h){
    float M = wmax64(m[h]);
    float S = wsum64(s[h] * expf(m[h] - M));
    M2[h] = M;
    rd[h] = 1.f / (S + 1e-16f);
  }
  for (int sl = beg + l; sl < end; sl += 64){
    f32x4 a = *(const f32x4*)(wgt + 4*(size_t)sl);
    #pragma unroll
    for (int h = 0; h < 4; ++h) a[h] = expf(a[h] - M2[h]) * rd[h];
    *(f32x4*)(wgt + 4*(size_t)sl) = a;
  }
}

__global__ __launch_bounds__(64) void k_stats2(
    const float* __restrict__ as2, const float* __restrict__ ad2,
    const int* __restrict__ rowptr, const int* __restrict__ csrc,
    float* __restrict__ wgt, int n)
{
  int i = blockIdx.x;
  int l = threadIdx.x;
  int beg = rowptr[i], end = rowptr[i+1];
  float adv = ad2[i];
  float m = -1e30f, s = 0.f;
  for (int sl = beg + l; sl < end; sl += 64){
    float a = lrelu(as2[csrc[sl]] + adv);
    wgt[sl] = a;
    if (a <= m) s += expf(a - m);
    else { s = s*expf(m - a) + 1.f; m = a; }
  }
  float M = wmax64(m);
  float S = wsum64(s * expf(m - M));
  float rd = 1.f / (S + 1e-16f);
  for (int sl = beg + l; sl < end; sl += 64)
    wgt[sl] = expf(wgt[sl] - M) * rd;
}

// ---------------- conv1 aggregate: wave per node, 4-edge unroll ----------------
__global__ __launch_bounds__(64) void k_gagg1(
    const ushort* __restrict__ xb, const float* __restrict__ wgt,
    const int* __restrict__ rowptr, const int* __restrict__ csrc,
    ushort* __restrict__ xagg, int n)
{
  int i = blockIdx.x;
  int l = threadIdx.x;
  int beg = rowptr[i], end = rowptr[i+1];
  float acc0[4] = {0.f,0.f,0.f,0.f};
  float acc1[4] = {0.f,0.f,0.f,0.f};

  int e = beg;
  for (; e + 3 < end; e += 4){
    int s0 = __builtin_nontemporal_load(csrc + e);
    int s1 = __builtin_nontemporal_load(csrc + e + 1);
    int s2 = __builtin_nontemporal_load(csrc + e + 2);
    int s3 = __builtin_nontemporal_load(csrc + e + 3);
    f32x4 w0 = *(const f32x4*)(wgt + 4*(size_t)e);
    f32x4 w1 = *(const f32x4*)(wgt + 4*(size_t)(e+1));
    f32x4 w2 = *(const f32x4*)(wgt + 4*(size_t)(e+2));
    f32x4 w3 = *(const f32x4*)(wgt + 4*(size_t)(e+3));
    ushort2 u0 = *(const ushort2*)(xb + (size_t)s0*IN_CH + 2*l);
    ushort2 u1 = *(const ushort2*)(xb + (size_t)s1*IN_CH + 2*l);
    ushort2 u2 = *(const ushort2*)(xb + (size_t)s2*IN_CH + 2*l);
    ushort2 u3 = *(const ushort2*)(xb + (size_t)s3*IN_CH + 2*l);
    float a0 = b2f(u0.x), b0 = b2f(u0.y);
    float a1 = b2f(u1.x), b1 = b2f(u1.y);
    float a2 = b2f(u2.x), b2 = b2f(u2.y);
    float a3 = b2f(u3.x), b3 = b2f(u3.y);
    #pragma unroll
    for (int h = 0; h < 4; ++h){
      acc0[h] += w0[h]*a0 + w1[h]*a1 + w2[h]*a2 + w3[h]*a3;
      acc1[h] += w0[h]*b0 + w1[h]*b1 + w2[h]*b2 + w3[h]*b3;
    }
  }
  for (; e < end; ++e){
    int s0 = csrc[e];
    f32x4 w0 = *(const f32x4*)(wgt + 4*(size_t)e);
    ushort2 u0 = *(const ushort2*)(xb + (size_t)s0*IN_CH + 2*l);
    float a0 = b2f(u0.x), b0 = b2f(u0.y);
    #pragma unroll
    for (int h = 0; h < 4; ++h){
      acc0[h] += w0[h]*a0;
      acc1[h] += w0[h]*b0;
    }
  }
  #pragma unroll
  for (int h = 0; h < 4; ++h){
    ushort2 o; o.x = f2b(acc0[h]); o.y = f2b(acc1[h]);
    *(ushort2*)(xagg + (size_t)i*512 + h*128 + 2*l) = o;
  }
}

// ---------------- conv2 aggregate: 16-lane quarters, 4 edges in flight ----------
__global__ __launch_bounds__(64) void k_gagg2(
    const ushort* __restrict__ h2b, const float* __restrict__ wgt,
    const int* __restrict__ rowptr, const int* __restrict__ csrc,
    const float* __restrict__ bias, ushort* __restrict__ z2b, int n)
{
  int i = blockIdx.x;
  int l = threadIdx.x;
  int q = l >> 4;             // 0..3
  int c4 = (l & 15) * 4;      // 4 channels per lane
  int beg = rowptr[i], end = rowptr[i+1];
  float a0 = 0.f, a1 = 0.f, a2 = 0.f, a3 = 0.f;
  for (int sl = beg + q; sl < end; sl += 4){
    int src = __builtin_nontemporal_load(csrc + sl);
    float w = __builtin_nontemporal_load(wgt + sl);
    ushort4 u = *(const ushort4*)(h2b + (size_t)src*OUT_CH + c4);
    a0 += w * b2f(u.x);
    a1 += w * b2f(u.y);
    a2 += w * b2f(u.z);
    a3 += w * b2f(u.w);
  }
  a0 += __shfl_xor(a0, 32, 64); a0 += __shfl_xor(a0, 16, 64);
  a1 += __shfl_xor(a1, 32, 64); a1 += __shfl_xor(a1, 16, 64);
  a2 += __shfl_xor(a2, 32, 64); a2 += __shfl_xor(a2, 16, 64);
  a3 += __shfl_xor(a3, 32, 64); a3 += __shfl_xor(a3, 16, 64);
  if (q == 0){
    ushort4 o;
    o.x = f2b(a0 + bias[c4]);
    o.y = f2b(a1 + bias[c4+1]);
    o.z = f2b(a2 + bias[c4+2]);
    o.w = f2b(a3 + bias[c4+3]);
    *(ushort4*)(z2b + (size_t)i*OUT_CH + c4) = o;
  }
}

// ---------------- bf16 MFMA GEMM, BM=128, BN=64, BK=64, strided, batched-z ----
template<bool RELU_BIAS>
__global__ __launch_bounds__(256) void k_gemm2(
    const ushort* __restrict__ A, const ushort* __restrict__ Bt,
    ushort* __restrict__ Cb, const float* __restrict__ bias,
    int M, int K, int lda, int ldc, int aZ, int bZ, int cZ)
{
  constexpr int BM = 128, BN = 64, NF = 2;
  __shared__ uint4 As[BM*8];
  __shared__ uint4 Bs[BN*8];
  int tid = threadIdx.x;
  int wave = tid >> 6, lane = tid & 63;
  int wr = wave >> 1, wc = wave & 1;
  int bm = blockIdx.y * BM;
  int z = blockIdx.z;
  const ushort* Az = A + (size_t)z*aZ;
  const ushort* Bz = Bt + (size_t)z*bZ;
  int g = lane >> 4, lr = lane & 15;

  f32x4 acc[4][NF];
  #pragma unroll
  for (int m = 0; m < 4; ++m)
    #pragma unroll
    for (int n = 0; n < NF; ++n) acc[m][n] = (f32x4)(0.f);

  for (int k0 = 0; k0 < K; k0 += 64){
    for (int idx = tid; idx < BM*8; idx += 256){
      int r = idx >> 3, c = idx & 7;
      int gr = bm + r;
      uint4 v = make_uint4(0u,0u,0u,0u);
      if (gr < M) v = *(const uint4*)(Az + (size_t)gr*lda + k0 + c*8);
      As[r*8 + (c ^ (r & 7))] = v;
    }
    for (int idx = tid; idx < BN*8; idx += 256){
      int r = idx >> 3, c = idx & 7;
      uint4 v = *(const uint4*)(Bz + (size_t)r*K + k0 + c*8);
      Bs[r*8 + (c ^ (r & 7))] = v;
    }
    __syncthreads();
    #pragma unroll
    for (int kk = 0; kk < 2; ++kk){
      short8v af[4], bf[NF];
      #pragma unroll
      for (int m = 0; m < 4; ++m){
        int r = wr*64 + m*16 + lr;
        int c = kk*4 + g;
        af[m] = *(const short8v*)&As[r*8 + (c ^ (r & 7))];
      }
      #pragma unroll
      for (int n = 0; n < NF; ++n){
        int r = wc*32 + n*16 + lr;
        int c = kk*4 + g;
        bf[n] = *(const short8v*)&Bs[r*8 + (c ^ (r & 7))];
      }
      #pragma unroll
      for (int m = 0; m < 4; ++m)
        #pragma unroll
        for (int n = 0; n < NF; ++n)
          acc[m][n] = __builtin_amdgcn_mfma_f32_16x16x32_bf16(af[m], bf[n], acc[m][n], 0, 0, 0);
    }
    __syncthreads();
  }
  #pragma unroll
  for (int m = 0; m < 4; ++m){
    #pragma unroll
    for (int q = 0; q < 4; ++q){
      int row = bm + wr*64 + m*16 + g*4 + q;
      if (row < M){
        #pragma unroll
        for (int n = 0; n < NF; ++n){
          int col = wc*32 + n*16 + lr;
          float v = acc[m][n][q];
          if (RELU_BIAS) v = fmaxf(v + bias[cZ*z + col], 0.f);
          Cb[(size_t)row*ldc + cZ*z + col] = f2b(v);
        }
      }
    }
  }
}

// ---------------- decoder: 2 edges (pos[k], neg[k]) per 8-lane group ----------
__global__ void k_decode(const ushort* __restrict__ z2b, const int* __restrict__ pos,
                         const int* __restrict__ neg, float* __restrict__ out, int e){
  int g = blockIdx.x*256 + threadIdx.x;
  int k = g >> 3;
  int sub = g & 7;
  if (k >= e) return;
  int a0 = __builtin_nontemporal_load(pos + k);
  int b0 = __builtin_nontemporal_load(pos + e + k);
  int a1 = __builtin_nontemporal_load(neg + k);
  int b1 = __builtin_nontemporal_load(neg + e + k);
  uint4 ua0 = *(const uint4*)(z2b + (size_t)a0*OUT_CH + sub*8);
  uint4 ub0 = *(const uint4*)(z2b + (size_t)b0*OUT_CH + sub*8);
  uint4 ua1 = *(const uint4*)(z2b + (size_t)a1*OUT_CH + sub*8);
  uint4 ub1 = *(const uint4*)(z2b + (size_t)b1*OUT_CH + sub*8);
  float p0 = dot2(ua0.x, ub0.x) + dot2(ua0.y, ub0.y) + dot2(ua0.z, ub0.z) + dot2(ua0.w, ub0.w);
  float p1 = dot2(ua1.x, ub1.x) + dot2(ua1.y, ub1.y) + dot2(ua1.z, ub1.z) + dot2(ua1.w, ub1.w);
  p0 += __shfl_xor(p0, 4, 64); p1 += __shfl_xor(p1, 4, 64);
  p0 += __shfl_xor(p0, 2, 64); p1 += __shfl_xor(p1, 2, 64);
  p0 += __shfl_xor(p0, 1, 64); p1 += __shfl_xor(p1, 1, 64);
  if (sub == 0){
    __builtin_nontemporal_store(p0, out + k);
    __builtin_nontemporal_store(p1, out + e + k);
  }
}

extern "C" void kernel_launch(void* const* d_in, const int* in_sizes, int n_in,
                              void* d_out, int out_size, void* d_ws, size_t ws_size,
                              hipStream_t stream) {
  const float* x        = (const float*)d_in[0];
  const int*   pos      = (const int*)d_in[1];
  const int*   neg      = (const int*)d_in[2];
  const float* W1       = (const float*)d_in[3];
  const float* att_src1 = (const float*)d_in[4];
  const float* att_dst1 = (const float*)d_in[5];
  const float* b1       = (const float*)d_in[6];
  const float* W2       = (const float*)d_in[7];
  const float* att_src2 = (const float*)d_in[8];
  const float* att_dst2 = (const float*)d_in[9];
  const float* b2       = (const float*)d_in[10];
  float* out = (float*)d_out;

  const int N = in_sizes[0] / IN_CH;   // 50000
  const int E = in_sizes[1] / 2;       // 800000
  const int NNZ = E + N;               // edges + self-loops
  const int NB = (N + NPB - 1) / NPB;  // 391 buckets

  char* w = (char*)d_ws;
  ushort* xb   = (ushort*)w;  w += (size_t)N*IN_CH*2;
  ushort* xagg = (ushort*)w;  w += (size_t)N*512*2;          // 51.2MB; sub-reused below
  ushort* z1b  = (ushort*)w;  w += (size_t)N*C1*2;
  float* wgt   = (float*)w;   w += (size_t)NNZ*4*4;
  float* as1   = (float*)w;   w += (size_t)N*4*4;
  float* ad1   = (float*)w;   w += (size_t)N*4*4;
  float* as2   = (float*)w;   w += (size_t)N*4;
  float* ad2   = (float*)w;   w += (size_t)N*4;
  ushort* W1t  = (ushort*)w;  w += (size_t)C1*IN_CH*2;
  ushort* W2t  = (ushort*)w;  w += (size_t)OUT_CH*C1*2;
  float* was4  = (float*)w;   w += 512*4;
  float* wad4  = (float*)w;   w += 512*4;
  float* w2s   = (float*)w;   w += 256*4;
  float* w2d   = (float*)w;   w += 256*4;
  int* deg     = (int*)w;     w += (size_t)N*4;
  int* rowptr  = (int*)w;     w += (size_t)(N+1)*4;
  int* bsum    = (int*)w;     w += (size_t)256*4;
  int* ebase   = (int*)w;     w += (size_t)512*4;
  int* ecnt    = (int*)w;     w += (size_t)512*4;
  unsigned* ebuf = (unsigned*)w; w += (size_t)E*4;
  int* csrc    = (int*)w;     w += (size_t)NNZ*4;

  // sub-allocations inside xagg (region dead after z1 GEMM):
  ushort* h2b = xagg;                                  // 6.4MB
  ushort* z2b = xagg + (size_t)N*OUT_CH;               // 6.4MB

  int eb = (E + 255)/256;
  int nb = (N + 255)/256;
  const int* pdst = pos + E;

  k_init<<<nb, 256, 0, stream>>>(deg, N);
  k_hist<<<eb, 256, 0, stream>>>(pdst, deg, E);
  k_blocksum<<<nb, 256, 0, stream>>>(deg, bsum, N);
  k_scanb<<<1, 256, 0, stream>>>(bsum, nb);
  k_scanfinal<<<nb, 256, 0, stream>>>(deg, bsum, rowptr, csrc, N);
  k_ebase<<<1, 512, 0, stream>>>(rowptr, ebase, ecnt, NB, N);
  k_binedges<<<eb, 256, 0, stream>>>(pos, pdst, ebase, ecnt, ebuf, E);
  k_fillcsr<<<NB, 256, 0, stream>>>(ebuf, ebase, ecnt, rowptr, csrc, N);

  k_tw<<<(IN_CH*C1 + 255)/256, 256, 0, stream>>>(W1, W1t, IN_CH, C1);
  k_tw<<<(C1*OUT_CH + 255)/256, 256, 0, stream>>>(W2, W2t, C1, OUT_CH);
  k_folds<<<2, 512, 0, stream>>>(W1, att_src1, att_dst1, W2, att_src2, att_dst2,
                                 was4, wad4, w2s, w2d);

  k_fattc<<<N, 64, 0, stream>>>(x, was4, wad4, xb, as1, ad1, N);
  k_stats1<<<N, 64, 0, stream>>>(as1, ad1, rowptr, csrc, wgt, N);
  k_gagg1<<<N, 64, 0, stream>>>(xb, wgt, rowptr, csrc, xagg, N);

  {  // z1 = relu(blockdiag(xagg_h @ W1_h) + b1), 4 heads via blockIdx.z
    dim3 g(1, (N + 127)/128, 4);
    k_gemm2<true><<<g, 256, 0, stream>>>(xagg, W1t, z1b, b1,
        N, IN_CH, 512, C1, IN_CH, OUT_CH*IN_CH, OUT_CH);
  }
  k_fatt2<<<N, 64, 0, stream>>>(z1b, w2s, w2d, as2, ad2, N);

  {  // h2 = z1 @ W2
    dim3 g(1, (N + 127)/128, 1);
    k_gemm2<false><<<g, 256, 0, stream>>>(z1b, W2t, h2b, nullptr,
        N, C1, C1, OUT_CH, 0, 0, 0);
  }
  k_stats2<<<N, 64, 0, stream>>>(as2, ad2, rowptr, csrc, wgt, N);
  k_gagg2<<<N, 64, 0, stream>>>(h2b, wgt, rowptr, csrc, b2, z2b, N);

  int db = (int)(((size_t)E*8 + 255)/256);
  k_decode<<<db, 256, 0, stream>>>(z2b, pos, neg, out, E);
}

// Round 10
// 350.277 us; speedup vs baseline: 1.6889x; 1.6889x over previous
//
#include <hip/hip_runtime.h>
#include <hip/hip_bf16.h>
#include <math.h>

#define IN_CH 128
#define HID 64
#define HEADS 4
#define C1 (HEADS*HID)   // 256
#define OUT_CH 64

typedef __attribute__((ext_vector_type(8))) short short8v;
typedef __attribute__((ext_vector_type(4))) float f32x4;

__device__ __forceinline__ float lrelu(float x){ return x > 0.f ? x : 0.2f*x; }

__device__ __forceinline__ ushort f2b(float f){
  unsigned u = __builtin_bit_cast(unsigned, f);
  unsigned r = (u + 0x7FFF + ((u>>16)&1)) >> 16;
  return (ushort)r;
}
__device__ __forceinline__ float b2f(ushort b){
  unsigned u = ((unsigned)b) << 16;
  return __builtin_bit_cast(float, u);
}

__device__ __forceinline__ float wsum64(float v){
  #pragma unroll
  for (int m = 32; m >= 1; m >>= 1) v += __shfl_xor(v, m, 64);
  return v;
}
__device__ __forceinline__ float wmax64(float v){
  #pragma unroll
  for (int m = 32; m >= 1; m >>= 1) v = fmaxf(v, __shfl_xor(v, m, 64));
  return v;
}

__device__ __forceinline__ float dot2(unsigned ua, unsigned ub){
  float la = __builtin_bit_cast(float, ua << 16);
  float ha = __builtin_bit_cast(float, ua & 0xFFFF0000u);
  float lb = __builtin_bit_cast(float, ub << 16);
  float hb = __builtin_bit_cast(float, ub & 0xFFFF0000u);
  return la*lb + ha*hb;
}

// ---------------- CSR build (R8-style scatter, cursor fused into scanfinal) ----

__global__ void k_init(int* deg, int n){
  int i = blockIdx.x*256 + threadIdx.x;
  if (i < n) deg[i] = 1;               // self-loop slot
}

__global__ void k_hist(const int* __restrict__ dst, int* deg, int e){
  int i = blockIdx.x*256 + threadIdx.x;
  if (i < e) atomicAdd(&deg[dst[i]], 1);
}

__global__ void k_blocksum(const int* __restrict__ deg, int* bsum, int n){
  __shared__ int buf[256];
  int b = blockIdx.x, tid = threadIdx.x;
  int i = b*256 + tid;
  buf[tid] = (i < n) ? deg[i] : 0;
  __syncthreads();
  for (int off = 128; off > 0; off >>= 1){
    if (tid < off) buf[tid] += buf[tid + off];
    __syncthreads();
  }
  if (tid == 0) bsum[b] = buf[0];
}

__global__ void k_scanb(int* bsum, int nb){
  __shared__ int buf[256];
  int tid = threadIdx.x;
  int v = (tid < nb) ? bsum[tid] : 0;
  buf[tid] = v;
  __syncthreads();
  for (int off = 1; off < 256; off <<= 1){
    int t = (tid >= off) ? buf[tid - off] : 0;
    __syncthreads();
    buf[tid] += t;
    __syncthreads();
  }
  if (tid < nb) bsum[tid] = buf[tid] - v;
}

// rowptr + self-loop slot + cursor init (cursor[i] = rowptr[i])
__global__ void k_scanfinal(const int* __restrict__ deg, const int* __restrict__ bsum,
                            int* rowptr, int* cursor, int* csrc, int n){
  __shared__ int buf[256];
  int b = blockIdx.x, tid = threadIdx.x;
  int i = b*256 + tid;
  int v = (i < n) ? deg[i] : 0;
  buf[tid] = v;
  __syncthreads();
  for (int off = 1; off < 256; off <<= 1){
    int t = (tid >= off) ? buf[tid - off] : 0;
    __syncthreads();
    buf[tid] += t;
    __syncthreads();
  }
  if (i < n){
    int r = bsum[b] + buf[tid];       // rowptr[i+1]
    rowptr[i + 1] = r;
    cursor[i] = r - v;                // rowptr[i]
    csrc[r - 1] = i;                  // self-loop in last slot
  }
  if (b == 0 && tid == 0) rowptr[0] = 0;
}

__global__ void k_scatter(const int* __restrict__ src, const int* __restrict__ dst,
                          int* cursor, int* csrc, int e){
  int i = blockIdx.x*256 + threadIdx.x;
  if (i < e){
    int d = dst[i];
    int slot = atomicAdd(&cursor[d], 1);
    csrc[slot] = src[i];
  }
}

// ---------------- weight folds ----------------

__global__ void k_tw(const float* __restrict__ W, ushort* __restrict__ Wt, int K, int N){
  int i = blockIdx.x*256 + threadIdx.x;
  if (i < K*N){
    int k = i / N, c = i - k*N;
    Wt[(size_t)c*K + k] = f2b(W[i]);
  }
}

// block0: fold1 (512 thr); block1: fold2 (first 256 thr)
__global__ void k_folds(const float* __restrict__ W1, const float* __restrict__ as1v,
                        const float* __restrict__ ad1v, const float* __restrict__ W2,
                        const float* __restrict__ as2v, const float* __restrict__ ad2v,
                        float* was4, float* wad4, float* w2s, float* w2d){
  int tid = threadIdx.x;
  if (blockIdx.x == 0){
    int c = tid >> 2, h = tid & 3;
    float s = 0.f, d = 0.f;
    for (int j = 0; j < HID; ++j){
      float w = W1[c*C1 + h*HID + j];
      s += w * as1v[h*HID + j];
      d += w * ad1v[h*HID + j];
    }
    was4[tid] = s; wad4[tid] = d;
  } else if (tid < 256){
    float s = 0.f, d = 0.f;
    for (int o = 0; o < OUT_CH; ++o){
      float w = W2[tid*OUT_CH + o];
      s += w * as2v[o];
      d += w * ad2v[o];
    }
    w2s[tid] = s; w2d[tid] = d;
  }
}

// fused: cast x->bf16 + conv1 attention scores. wave per node, lane = 2 channels.
__global__ __launch_bounds__(64) void k_fattc(const float* __restrict__ x,
    const float* __restrict__ was4, const float* __restrict__ wad4,
    ushort* __restrict__ xb, float* __restrict__ as1, float* __restrict__ ad1, int n){
  int i = blockIdx.x;
  int l = threadIdx.x;
  float2 u = *(const float2*)(x + (size_t)i*IN_CH + 2*l);
  ushort2 o; o.x = f2b(u.x); o.y = f2b(u.y);
  *(ushort2*)(xb + (size_t)i*IN_CH + 2*l) = o;
  float v0 = u.x, v1 = u.y;
  f32x4 s0 = *(const f32x4*)(was4 + 8*l);
  f32x4 s1 = *(const f32x4*)(was4 + 8*l + 4);
  f32x4 d0 = *(const f32x4*)(wad4 + 8*l);
  f32x4 d1 = *(const f32x4*)(wad4 + 8*l + 4);
  f32x4 ps, pd;
  #pragma unroll
  for (int h = 0; h < 4; ++h){
    ps[h] = wsum64(v0*s0[h] + v1*s1[h]);
    pd[h] = wsum64(v0*d0[h] + v1*d1[h]);
  }
  if (l == 0){
    *(f32x4*)(as1 + 4*i) = ps;
    *(f32x4*)(ad1 + 4*i) = pd;
  }
}

// as2/ad2 from z1: wave per node, lane = 4 channels
__global__ __launch_bounds__(64) void k_fatt2(const ushort* __restrict__ z1b,
    const float* __restrict__ w2s, const float* __restrict__ w2d,
    float* __restrict__ as2, float* __restrict__ ad2, int n){
  int i = blockIdx.x;
  int l = threadIdx.x;
  ushort4 u = *(const ushort4*)(z1b + (size_t)i*C1 + 4*l);
  float v0 = b2f(u.x), v1 = b2f(u.y), v2 = b2f(u.z), v3 = b2f(u.w);
  f32x4 s = *(const f32x4*)(w2s + 4*l);
  f32x4 d = *(const f32x4*)(w2d + 4*l);
  float ps = wsum64(v0*s[0] + v1*s[1] + v2*s[2] + v3*s[3]);
  float pd = wsum64(v0*d[0] + v1*d[1] + v2*d[2] + v3*d[3]);
  if (l == 0){ as2[i] = ps; ad2[i] = pd; }
}

// ---------------- softmax stats + normalized weights ----------------
__global__ __launch_bounds__(64) void k_stats1(
    const float* __restrict__ as1, const float* __restrict__ ad1,
    const int* __restrict__ rowptr, const int* __restrict__ csrc,
    float* __restrict__ wgt, int n)
{
  int i = blockIdx.x;
  int l = threadIdx.x;
  int beg = rowptr[i], end = rowptr[i+1];
  f32x4 ad4 = *(const f32x4*)(ad1 + 4*i);

  f32x4 m = (f32x4)(-1e30f), s = (f32x4)(0.f);
  for (int sl = beg + l; sl < end; sl += 64){
    int sj = csrc[sl];
    f32x4 a4 = *(const f32x4*)(as1 + 4*sj);
    f32x4 al;
    #pragma unroll
    for (int h = 0; h < 4; ++h){
      float a = lrelu(a4[h] + ad4[h]);
      al[h] = a;
      if (a <= m[h]) s[h] += expf(a - m[h]);
      else { s[h] = s[h]*expf(m[h] - a) + 1.f; m[h] = a; }
    }
    *(f32x4*)(wgt + 4*(size_t)sl) = al;
  }
  f32x4 M2, rd;
  #pragma unroll
  for (int h = 0; h < 4; ++h){
    float M = wmax64(m[h]);
    float S = wsum64(s[h] * expf(m[h] - M));
    M2[h] = M;
    rd[h] = 1.f / (S + 1e-16f);
  }
  for (int sl = beg + l; sl < end; sl += 64){
    f32x4 a = *(const f32x4*)(wgt + 4*(size_t)sl);
    #pragma unroll
    for (int h = 0; h < 4; ++h) a[h] = expf(a[h] - M2[h]) * rd[h];
    *(f32x4*)(wgt + 4*(size_t)sl) = a;
  }
}

__global__ __launch_bounds__(64) void k_stats2(
    const float* __restrict__ as2, const float* __restrict__ ad2,
    const int* __restrict__ rowptr, const int* __restrict__ csrc,
    float* __restrict__ wgt, int n)
{
  int i = blockIdx.x;
  int l = threadIdx.x;
  int beg = rowptr[i], end = rowptr[i+1];
  float adv = ad2[i];
  float m = -1e30f, s = 0.f;
  for (int sl = beg + l; sl < end; sl += 64){
    float a = lrelu(as2[csrc[sl]] + adv);
    wgt[sl] = a;
    if (a <= m) s += expf(a - m);
    else { s = s*expf(m - a) + 1.f; m = a; }
  }
  float M = wmax64(m);
  float S = wsum64(s * expf(m - M));
  float rd = 1.f / (S + 1e-16f);
  for (int sl = beg + l; sl < end; sl += 64)
    wgt[sl] = expf(wgt[sl] - M) * rd;
}

// ---------------- conv1 aggregate: wave per node, 4-edge unroll ----------------
__global__ __launch_bounds__(64) void k_gagg1(
    const ushort* __restrict__ xb, const float* __restrict__ wgt,
    const int* __restrict__ rowptr, const int* __restrict__ csrc,
    ushort* __restrict__ xagg, int n)
{
  int i = blockIdx.x;
  int l = threadIdx.x;
  int beg = rowptr[i], end = rowptr[i+1];
  float acc0[4] = {0.f,0.f,0.f,0.f};
  float acc1[4] = {0.f,0.f,0.f,0.f};

  int e = beg;
  for (; e + 3 < end; e += 4){
    int s0 = __builtin_nontemporal_load(csrc + e);
    int s1 = __builtin_nontemporal_load(csrc + e + 1);
    int s2 = __builtin_nontemporal_load(csrc + e + 2);
    int s3 = __builtin_nontemporal_load(csrc + e + 3);
    f32x4 w0 = *(const f32x4*)(wgt + 4*(size_t)e);
    f32x4 w1 = *(const f32x4*)(wgt + 4*(size_t)(e+1));
    f32x4 w2 = *(const f32x4*)(wgt + 4*(size_t)(e+2));
    f32x4 w3 = *(const f32x4*)(wgt + 4*(size_t)(e+3));
    ushort2 u0 = *(const ushort2*)(xb + (size_t)s0*IN_CH + 2*l);
    ushort2 u1 = *(const ushort2*)(xb + (size_t)s1*IN_CH + 2*l);
    ushort2 u2 = *(const ushort2*)(xb + (size_t)s2*IN_CH + 2*l);
    ushort2 u3 = *(const ushort2*)(xb + (size_t)s3*IN_CH + 2*l);
    float a0 = b2f(u0.x), b0 = b2f(u0.y);
    float a1 = b2f(u1.x), b1 = b2f(u1.y);
    float a2 = b2f(u2.x), b2 = b2f(u2.y);
    float a3 = b2f(u3.x), b3 = b2f(u3.y);
    #pragma unroll
    for (int h = 0; h < 4; ++h){
      acc0[h] += w0[h]*a0 + w1[h]*a1 + w2[h]*a2 + w3[h]*a3;
      acc1[h] += w0[h]*b0 + w1[h]*b1 + w2[h]*b2 + w3[h]*b3;
    }
  }
  for (; e < end; ++e){
    int s0 = csrc[e];
    f32x4 w0 = *(const f32x4*)(wgt + 4*(size_t)e);
    ushort2 u0 = *(const ushort2*)(xb + (size_t)s0*IN_CH + 2*l);
    float a0 = b2f(u0.x), b0 = b2f(u0.y);
    #pragma unroll
    for (int h = 0; h < 4; ++h){
      acc0[h] += w0[h]*a0;
      acc1[h] += w0[h]*b0;
    }
  }
  #pragma unroll
  for (int h = 0; h < 4; ++h){
    ushort2 o; o.x = f2b(acc0[h]); o.y = f2b(acc1[h]);
    *(ushort2*)(xagg + (size_t)i*512 + h*128 + 2*l) = o;
  }
}

// ---------------- conv2 aggregate: 16-lane quarters, 4 edges in flight ----------
__global__ __launch_bounds__(64) void k_gagg2(
    const ushort* __restrict__ h2b, const float* __restrict__ wgt,
    const int* __restrict__ rowptr, const int* __restrict__ csrc,
    const float* __restrict__ bias, ushort* __restrict__ z2b, int n)
{
  int i = blockIdx.x;
  int l = threadIdx.x;
  int q = l >> 4;             // 0..3
  int c4 = (l & 15) * 4;      // 4 channels per lane
  int beg = rowptr[i], end = rowptr[i+1];
  float a0 = 0.f, a1 = 0.f, a2 = 0.f, a3 = 0.f;
  for (int sl = beg + q; sl < end; sl += 4){
    int src = __builtin_nontemporal_load(csrc + sl);
    float w = __builtin_nontemporal_load(wgt + sl);
    ushort4 u = *(const ushort4*)(h2b + (size_t)src*OUT_CH + c4);
    a0 += w * b2f(u.x);
    a1 += w * b2f(u.y);
    a2 += w * b2f(u.z);
    a3 += w * b2f(u.w);
  }
  a0 += __shfl_xor(a0, 32, 64); a0 += __shfl_xor(a0, 16, 64);
  a1 += __shfl_xor(a1, 32, 64); a1 += __shfl_xor(a1, 16, 64);
  a2 += __shfl_xor(a2, 32, 64); a2 += __shfl_xor(a2, 16, 64);
  a3 += __shfl_xor(a3, 32, 64); a3 += __shfl_xor(a3, 16, 64);
  if (q == 0){
    ushort4 o;
    o.x = f2b(a0 + bias[c4]);
    o.y = f2b(a1 + bias[c4+1]);
    o.z = f2b(a2 + bias[c4+2]);
    o.w = f2b(a3 + bias[c4+3]);
    *(ushort4*)(z2b + (size_t)i*OUT_CH + c4) = o;
  }
}

// ---------------- bf16 MFMA GEMM, BM=128, BN=64, BK=64, strided, batched-z ----
template<bool RELU_BIAS>
__global__ __launch_bounds__(256) void k_gemm2(
    const ushort* __restrict__ A, const ushort* __restrict__ Bt,
    ushort* __restrict__ Cb, const float* __restrict__ bias,
    int M, int K, int lda, int ldc, int aZ, int bZ, int cZ)
{
  constexpr int BM = 128, BN = 64, NF = 2;
  __shared__ uint4 As[BM*8];
  __shared__ uint4 Bs[BN*8];
  int tid = threadIdx.x;
  int wave = tid >> 6, lane = tid & 63;
  int wr = wave >> 1, wc = wave & 1;
  int bm = blockIdx.y * BM;
  int z = blockIdx.z;
  const ushort* Az = A + (size_t)z*aZ;
  const ushort* Bz = Bt + (size_t)z*bZ;
  int g = lane >> 4, lr = lane & 15;

  f32x4 acc[4][NF];
  #pragma unroll
  for (int m = 0; m < 4; ++m)
    #pragma unroll
    for (int n = 0; n < NF; ++n) acc[m][n] = (f32x4)(0.f);

  for (int k0 = 0; k0 < K; k0 += 64){
    for (int idx = tid; idx < BM*8; idx += 256){
      int r = idx >> 3, c = idx & 7;
      int gr = bm + r;
      uint4 v = make_uint4(0u,0u,0u,0u);
      if (gr < M) v = *(const uint4*)(Az + (size_t)gr*lda + k0 + c*8);
      As[r*8 + (c ^ (r & 7))] = v;
    }
    for (int idx = tid; idx < BN*8; idx += 256){
      int r = idx >> 3, c = idx & 7;
      uint4 v = *(const uint4*)(Bz + (size_t)r*K + k0 + c*8);
      Bs[r*8 + (c ^ (r & 7))] = v;
    }
    __syncthreads();
    #pragma unroll
    for (int kk = 0; kk < 2; ++kk){
      short8v af[4], bf[NF];
      #pragma unroll
      for (int m = 0; m < 4; ++m){
        int r = wr*64 + m*16 + lr;
        int c = kk*4 + g;
        af[m] = *(const short8v*)&As[r*8 + (c ^ (r & 7))];
      }
      #pragma unroll
      for (int n = 0; n < NF; ++n){
        int r = wc*32 + n*16 + lr;
        int c = kk*4 + g;
        bf[n] = *(const short8v*)&Bs[r*8 + (c ^ (r & 7))];
      }
      #pragma unroll
      for (int m = 0; m < 4; ++m)
        #pragma unroll
        for (int n = 0; n < NF; ++n)
          acc[m][n] = __builtin_amdgcn_mfma_f32_16x16x32_bf16(af[m], bf[n], acc[m][n], 0, 0, 0);
    }
    __syncthreads();
  }
  #pragma unroll
  for (int m = 0; m < 4; ++m){
    #pragma unroll
    for (int q = 0; q < 4; ++q){
      int row = bm + wr*64 + m*16 + g*4 + q;
      if (row < M){
        #pragma unroll
        for (int n = 0; n < NF; ++n){
          int col = wc*32 + n*16 + lr;
          float v = acc[m][n][q];
          if (RELU_BIAS) v = fmaxf(v + bias[cZ*z + col], 0.f);
          Cb[(size_t)row*ldc + cZ*z + col] = f2b(v);
        }
      }
    }
  }
}

// ---------------- decoder: 2 edges (pos[k], neg[k]) per 8-lane group ----------
__global__ void k_decode(const ushort* __restrict__ z2b, const int* __restrict__ pos,
                         const int* __restrict__ neg, float* __restrict__ out, int e){
  int g = blockIdx.x*256 + threadIdx.x;
  int k = g >> 3;
  int sub = g & 7;
  if (k >= e) return;
  int a0 = __builtin_nontemporal_load(pos + k);
  int b0 = __builtin_nontemporal_load(pos + e + k);
  int a1 = __builtin_nontemporal_load(neg + k);
  int b1 = __builtin_nontemporal_load(neg + e + k);
  uint4 ua0 = *(const uint4*)(z2b + (size_t)a0*OUT_CH + sub*8);
  uint4 ub0 = *(const uint4*)(z2b + (size_t)b0*OUT_CH + sub*8);
  uint4 ua1 = *(const uint4*)(z2b + (size_t)a1*OUT_CH + sub*8);
  uint4 ub1 = *(const uint4*)(z2b + (size_t)b1*OUT_CH + sub*8);
  float p0 = dot2(ua0.x, ub0.x) + dot2(ua0.y, ub0.y) + dot2(ua0.z, ub0.z) + dot2(ua0.w, ub0.w);
  float p1 = dot2(ua1.x, ub1.x) + dot2(ua1.y, ub1.y) + dot2(ua1.z, ub1.z) + dot2(ua1.w, ub1.w);
  p0 += __shfl_xor(p0, 4, 64); p1 += __shfl_xor(p1, 4, 64);
  p0 += __shfl_xor(p0, 2, 64); p1 += __shfl_xor(p1, 2, 64);
  p0 += __shfl_xor(p0, 1, 64); p1 += __shfl_xor(p1, 1, 64);
  if (sub == 0){
    __builtin_nontemporal_store(p0, out + k);
    __builtin_nontemporal_store(p1, out + e + k);
  }
}

extern "C" void kernel_launch(void* const* d_in, const int* in_sizes, int n_in,
                              void* d_out, int out_size, void* d_ws, size_t ws_size,
                              hipStream_t stream) {
  const float* x        = (const float*)d_in[0];
  const int*   pos      = (const int*)d_in[1];
  const int*   neg      = (const int*)d_in[2];
  const float* W1       = (const float*)d_in[3];
  const float* att_src1 = (const float*)d_in[4];
  const float* att_dst1 = (const float*)d_in[5];
  const float* b1       = (const float*)d_in[6];
  const float* W2       = (const float*)d_in[7];
  const float* att_src2 = (const float*)d_in[8];
  const float* att_dst2 = (const float*)d_in[9];
  const float* b2       = (const float*)d_in[10];
  float* out = (float*)d_out;

  const int N = in_sizes[0] / IN_CH;   // 50000
  const int E = in_sizes[1] / 2;       // 800000
  const int NNZ = E + N;               // edges + self-loops

  char* w = (char*)d_ws;
  ushort* xb   = (ushort*)w;  w += (size_t)N*IN_CH*2;
  ushort* xagg = (ushort*)w;  w += (size_t)N*512*2;          // 51.2MB; sub-reused below
  ushort* z1b  = (ushort*)w;  w += (size_t)N*C1*2;
  float* wgt   = (float*)w;   w += (size_t)NNZ*4*4;
  float* as1   = (float*)w;   w += (size_t)N*4*4;
  float* ad1   = (float*)w;   w += (size_t)N*4*4;
  float* as2   = (float*)w;   w += (size_t)N*4;
  float* ad2   = (float*)w;   w += (size_t)N*4;
  ushort* W1t  = (ushort*)w;  w += (size_t)C1*IN_CH*2;
  ushort* W2t  = (ushort*)w;  w += (size_t)OUT_CH*C1*2;
  float* was4  = (float*)w;   w += 512*4;
  float* wad4  = (float*)w;   w += 512*4;
  float* w2s   = (float*)w;   w += 256*4;
  float* w2d   = (float*)w;   w += 256*4;
  int* deg     = (int*)w;     w += (size_t)N*4;
  int* rowptr  = (int*)w;     w += (size_t)(N+1)*4;
  int* cursor  = (int*)w;     w += (size_t)N*4;
  int* bsum    = (int*)w;     w += (size_t)256*4;
  int* csrc    = (int*)w;     w += (size_t)NNZ*4;

  // sub-allocations inside xagg (region dead after z1 GEMM):
  ushort* h2b = xagg;                                  // 6.4MB
  ushort* z2b = xagg + (size_t)N*OUT_CH;               // 6.4MB

  int eb = (E + 255)/256;
  int nb = (N + 255)/256;
  const int* pdst = pos + E;

  k_init<<<nb, 256, 0, stream>>>(deg, N);
  k_hist<<<eb, 256, 0, stream>>>(pdst, deg, E);
  k_blocksum<<<nb, 256, 0, stream>>>(deg, bsum, N);
  k_scanb<<<1, 256, 0, stream>>>(bsum, nb);
  k_scanfinal<<<nb, 256, 0, stream>>>(deg, bsum, rowptr, cursor, csrc, N);
  k_scatter<<<eb, 256, 0, stream>>>(pos, pdst, cursor, csrc, E);

  k_tw<<<(IN_CH*C1 + 255)/256, 256, 0, stream>>>(W1, W1t, IN_CH, C1);
  k_tw<<<(C1*OUT_CH + 255)/256, 256, 0, stream>>>(W2, W2t, C1, OUT_CH);
  k_folds<<<2, 512, 0, stream>>>(W1, att_src1, att_dst1, W2, att_src2, att_dst2,
                                 was4, wad4, w2s, w2d);

  k_fattc<<<N, 64, 0, stream>>>(x, was4, wad4, xb, as1, ad1, N);
  k_stats1<<<N, 64, 0, stream>>>(as1, ad1, rowptr, csrc, wgt, N);
  k_gagg1<<<N, 64, 0, stream>>>(xb, wgt, rowptr, csrc, xagg, N);

  {  // z1 = relu(blockdiag(xagg_h @ W1_h) + b1), 4 heads via blockIdx.z
    dim3 g(1, (N + 127)/128, 4);
    k_gemm2<true><<<g, 256, 0, stream>>>(xagg, W1t, z1b, b1,
        N, IN_CH, 512, C1, IN_CH, OUT_CH*IN_CH, OUT_CH);
  }
  k_fatt2<<<N, 64, 0, stream>>>(z1b, w2s, w2d, as2, ad2, N);

  {  // h2 = z1 @ W2
    dim3 g(1, (N + 127)/128, 1);
    k_gemm2<false><<<g, 256, 0, stream>>>(z1b, W2t, h2b, nullptr,
        N, C1, C1, OUT_CH, 0, 0, 0);
  }
  k_stats2<<<N, 64, 0, stream>>>(as2, ad2, rowptr, csrc, wgt, N);
  k_gagg2<<<N, 64, 0, stream>>>(h2b, wgt, rowptr, csrc, b2, z2b, N);

  int db = (int)(((size_t)E*8 + 255)/256);
  k_decode<<<db, 256, 0, stream>>>(z2b, pos, neg, out, E);
}

// Round 11
// 317.992 us; speedup vs baseline: 1.8603x; 1.1015x over previous
//
#include <hip/hip_runtime.h>
#include <hip/hip_bf16.h>
#include <math.h>

#define IN_CH 128
#define HID 64
#define HEADS 4
#define C1 (HEADS*HID)   // 256
#define OUT_CH 64

typedef __attribute__((ext_vector_type(8))) short short8v;
typedef __attribute__((ext_vector_type(4))) float f32x4;

__device__ __forceinline__ float lrelu(float x){ return x > 0.f ? x : 0.2f*x; }

__device__ __forceinline__ ushort f2b(float f){
  unsigned u = __builtin_bit_cast(unsigned, f);
  unsigned r = (u + 0x7FFF + ((u>>16)&1)) >> 16;
  return (ushort)r;
}
__device__ __forceinline__ float b2f(ushort b){
  unsigned u = ((unsigned)b) << 16;
  return __builtin_bit_cast(float, u);
}

__device__ __forceinline__ float wsum64(float v){
  #pragma unroll
  for (int m = 32; m >= 1; m >>= 1) v += __shfl_xor(v, m, 64);
  return v;
}
__device__ __forceinline__ float wmax64(float v){
  #pragma unroll
  for (int m = 32; m >= 1; m >>= 1) v = fmaxf(v, __shfl_xor(v, m, 64));
  return v;
}

__device__ __forceinline__ float dot2(unsigned ua, unsigned ub){
  float la = __builtin_bit_cast(float, ua << 16);
  float ha = __builtin_bit_cast(float, ua & 0xFFFF0000u);
  float lb = __builtin_bit_cast(float, ub << 16);
  float hb = __builtin_bit_cast(float, ub & 0xFFFF0000u);
  return la*lb + ha*hb;
}

// ---------------- CSR build ----------------

__global__ void k_init(int* deg, int n){
  int i = blockIdx.x*256 + threadIdx.x;
  if (i < n) deg[i] = 1;               // self-loop slot
}

__global__ void k_hist(const int* __restrict__ dst, int* deg, int e){
  int i = blockIdx.x*256 + threadIdx.x;
  if (i < e) atomicAdd(&deg[dst[i]], 1);
}

__global__ void k_blocksum(const int* __restrict__ deg, int* bsum, int n){
  __shared__ int buf[256];
  int b = blockIdx.x, tid = threadIdx.x;
  int i = b*256 + tid;
  buf[tid] = (i < n) ? deg[i] : 0;
  __syncthreads();
  for (int off = 128; off > 0; off >>= 1){
    if (tid < off) buf[tid] += buf[tid + off];
    __syncthreads();
  }
  if (tid == 0) bsum[b] = buf[0];
}

__global__ void k_scanb(int* bsum, int nb){
  __shared__ int buf[256];
  int tid = threadIdx.x;
  int v = (tid < nb) ? bsum[tid] : 0;
  buf[tid] = v;
  __syncthreads();
  for (int off = 1; off < 256; off <<= 1){
    int t = (tid >= off) ? buf[tid - off] : 0;
    __syncthreads();
    buf[tid] += t;
    __syncthreads();
  }
  if (tid < nb) bsum[tid] = buf[tid] - v;
}

// rowptr + self-loop slot + cursor init (cursor[i] = rowptr[i])
__global__ void k_scanfinal(const int* __restrict__ deg, const int* __restrict__ bsum,
                            int* rowptr, int* cursor, int* csrc, int n){
  __shared__ int buf[256];
  int b = blockIdx.x, tid = threadIdx.x;
  int i = b*256 + tid;
  int v = (i < n) ? deg[i] : 0;
  buf[tid] = v;
  __syncthreads();
  for (int off = 1; off < 256; off <<= 1){
    int t = (tid >= off) ? buf[tid - off] : 0;
    __syncthreads();
    buf[tid] += t;
    __syncthreads();
  }
  if (i < n){
    int r = bsum[b] + buf[tid];       // rowptr[i+1]
    rowptr[i + 1] = r;
    cursor[i] = r - v;                // rowptr[i]
    csrc[r - 1] = i;                  // self-loop in last slot
  }
  if (b == 0 && tid == 0) rowptr[0] = 0;
}

__global__ void k_scatter(const int* __restrict__ src, const int* __restrict__ dst,
                          int* cursor, int* csrc, int e){
  int i = blockIdx.x*256 + threadIdx.x;
  if (i < e){
    int d = dst[i];
    int slot = atomicAdd(&cursor[d], 1);
    __builtin_nontemporal_store(src[i], csrc + slot);
  }
}

// ---------------- weight folds ----------------

__global__ void k_tw(const float* __restrict__ W, ushort* __restrict__ Wt, int K, int N){
  int i = blockIdx.x*256 + threadIdx.x;
  if (i < K*N){
    int k = i / N, c = i - k*N;
    Wt[(size_t)c*K + k] = f2b(W[i]);
  }
}

// block0: fold1 (512 thr); block1: fold2 (first 256 thr)
__global__ void k_folds(const float* __restrict__ W1, const float* __restrict__ as1v,
                        const float* __restrict__ ad1v, const float* __restrict__ W2,
                        const float* __restrict__ as2v, const float* __restrict__ ad2v,
                        float* was4, float* wad4, float* w2s, float* w2d){
  int tid = threadIdx.x;
  if (blockIdx.x == 0){
    int c = tid >> 2, h = tid & 3;
    float s = 0.f, d = 0.f;
    for (int j = 0; j < HID; ++j){
      float w = W1[c*C1 + h*HID + j];
      s += w * as1v[h*HID + j];
      d += w * ad1v[h*HID + j];
    }
    was4[tid] = s; wad4[tid] = d;
  } else if (tid < 256){
    float s = 0.f, d = 0.f;
    for (int o = 0; o < OUT_CH; ++o){
      float w = W2[tid*OUT_CH + o];
      s += w * as2v[o];
      d += w * ad2v[o];
    }
    w2s[tid] = s; w2d[tid] = d;
  }
}

// fused: cast x->bf16 + conv1 attention scores. wave per node, lane = 2 channels.
__global__ __launch_bounds__(64) void k_fattc(const float* __restrict__ x,
    const float* __restrict__ was4, const float* __restrict__ wad4,
    ushort* __restrict__ xb, float* __restrict__ as1, float* __restrict__ ad1, int n){
  int i = blockIdx.x;
  int l = threadIdx.x;
  float2 u = *(const float2*)(x + (size_t)i*IN_CH + 2*l);
  ushort2 o; o.x = f2b(u.x); o.y = f2b(u.y);
  *(ushort2*)(xb + (size_t)i*IN_CH + 2*l) = o;
  float v0 = u.x, v1 = u.y;
  f32x4 s0 = *(const f32x4*)(was4 + 8*l);
  f32x4 s1 = *(const f32x4*)(was4 + 8*l + 4);
  f32x4 d0 = *(const f32x4*)(wad4 + 8*l);
  f32x4 d1 = *(const f32x4*)(wad4 + 8*l + 4);
  f32x4 ps, pd;
  #pragma unroll
  for (int h = 0; h < 4; ++h){
    ps[h] = wsum64(v0*s0[h] + v1*s1[h]);
    pd[h] = wsum64(v0*d0[h] + v1*d1[h]);
  }
  if (l == 0){
    *(f32x4*)(as1 + 4*i) = ps;
    *(f32x4*)(ad1 + 4*i) = pd;
  }
}

// as2/ad2 from z1: wave per node, lane = 4 channels
__global__ __launch_bounds__(64) void k_fatt2(const ushort* __restrict__ z1b,
    const float* __restrict__ w2s, const float* __restrict__ w2d,
    float* __restrict__ as2, float* __restrict__ ad2, int n){
  int i = blockIdx.x;
  int l = threadIdx.x;
  ushort4 u = *(const ushort4*)(z1b + (size_t)i*C1 + 4*l);
  float v0 = b2f(u.x), v1 = b2f(u.y), v2 = b2f(u.z), v3 = b2f(u.w);
  f32x4 s = *(const f32x4*)(w2s + 4*l);
  f32x4 d = *(const f32x4*)(w2d + 4*l);
  float ps = wsum64(v0*s[0] + v1*s[1] + v2*s[2] + v3*s[3]);
  float pd = wsum64(v0*d[0] + v1*d[1] + v2*d[2] + v3*d[3]);
  if (l == 0){ as2[i] = ps; ad2[i] = pd; }
}

// ---------------- conv1 fused softmax+aggregate: wave per node ----------------
__global__ __launch_bounds__(64) void k_fagg1(
    const ushort* __restrict__ xb, const float* __restrict__ as1,
    const float* __restrict__ ad1, const int* __restrict__ rowptr,
    const int* __restrict__ csrc, ushort* __restrict__ xagg, int n)
{
  int i = blockIdx.x;
  int l = threadIdx.x;
  int beg = rowptr[i], end = rowptr[i+1];
  f32x4 ad4 = *(const f32x4*)(ad1 + 4*i);
  __shared__ int   s_src[64];
  __shared__ float s_w[4][64];

  // pass A: lane-strided online max/denom over all slots
  f32x4 m = (f32x4)(-1e30f), s = (f32x4)(0.f);
  for (int sl = beg + l; sl < end; sl += 64){
    int sj = csrc[sl];
    f32x4 a4 = *(const f32x4*)(as1 + 4*sj);
    #pragma unroll
    for (int h = 0; h < 4; ++h){
      float a = lrelu(a4[h] + ad4[h]);
      if (a <= m[h]) s[h] += expf(a - m[h]);
      else { s[h] = s[h]*expf(m[h] - a) + 1.f; m[h] = a; }
    }
  }
  f32x4 M, rd;
  #pragma unroll
  for (int h = 0; h < 4; ++h){
    float Mh = wmax64(m[h]);
    float Sh = wsum64(s[h] * expf(m[h] - Mh));
    M[h] = Mh;
    rd[h] = 1.f / (Sh + 1e-16f);
  }

  // pass B: per-64-edge chunk, one lane computes one edge's weights into LDS,
  // then all lanes aggregate with LDS-broadcast weights.
  float acc0[4] = {0.f,0.f,0.f,0.f};
  float acc1[4] = {0.f,0.f,0.f,0.f};
  for (int cs = beg; cs < end; cs += 64){
    int cn = min(64, end - cs);
    __syncthreads();
    if (l < cn){
      int sj = csrc[cs + l];
      s_src[l] = sj;
      f32x4 a4 = *(const f32x4*)(as1 + 4*sj);
      #pragma unroll
      for (int h = 0; h < 4; ++h)
        s_w[h][l] = expf(lrelu(a4[h] + ad4[h]) - M[h]) * rd[h];
    }
    __syncthreads();
    int e = 0;
    for (; e + 3 < cn; e += 4){
      int s0 = s_src[e], s1 = s_src[e+1], s2 = s_src[e+2], s3 = s_src[e+3];
      ushort2 u0 = *(const ushort2*)(xb + (size_t)s0*IN_CH + 2*l);
      ushort2 u1 = *(const ushort2*)(xb + (size_t)s1*IN_CH + 2*l);
      ushort2 u2 = *(const ushort2*)(xb + (size_t)s2*IN_CH + 2*l);
      ushort2 u3 = *(const ushort2*)(xb + (size_t)s3*IN_CH + 2*l);
      float a0 = b2f(u0.x), b0 = b2f(u0.y);
      float a1 = b2f(u1.x), b1 = b2f(u1.y);
      float a2 = b2f(u2.x), b2 = b2f(u2.y);
      float a3 = b2f(u3.x), b3 = b2f(u3.y);
      #pragma unroll
      for (int h = 0; h < 4; ++h){
        acc0[h] += s_w[h][e]*a0 + s_w[h][e+1]*a1 + s_w[h][e+2]*a2 + s_w[h][e+3]*a3;
        acc1[h] += s_w[h][e]*b0 + s_w[h][e+1]*b1 + s_w[h][e+2]*b2 + s_w[h][e+3]*b3;
      }
    }
    for (; e < cn; ++e){
      int s0 = s_src[e];
      ushort2 u0 = *(const ushort2*)(xb + (size_t)s0*IN_CH + 2*l);
      float a0 = b2f(u0.x), b0 = b2f(u0.y);
      #pragma unroll
      for (int h = 0; h < 4; ++h){
        acc0[h] += s_w[h][e]*a0;
        acc1[h] += s_w[h][e]*b0;
      }
    }
  }
  #pragma unroll
  for (int h = 0; h < 4; ++h){
    ushort2 o; o.x = f2b(acc0[h]); o.y = f2b(acc1[h]);
    *(ushort2*)(xagg + (size_t)i*512 + h*128 + 2*l) = o;
  }
}

// ---------------- conv2 fused softmax+aggregate: wave per node ----------------
__global__ __launch_bounds__(64) void k_fagg2(
    const ushort* __restrict__ h2b, const float* __restrict__ as2,
    const float* __restrict__ ad2, const int* __restrict__ rowptr,
    const int* __restrict__ csrc, const float* __restrict__ bias,
    ushort* __restrict__ z2b, int n)
{
  int i = blockIdx.x;
  int l = threadIdx.x;
  int beg = rowptr[i], end = rowptr[i+1];
  float adv = ad2[i];
  __shared__ int   s_src[64];
  __shared__ float s_w[64];

  // pass A
  float m = -1e30f, s = 0.f;
  for (int sl = beg + l; sl < end; sl += 64){
    float a = lrelu(as2[csrc[sl]] + adv);
    if (a <= m) s += expf(a - m);
    else { s = s*expf(m - a) + 1.f; m = a; }
  }
  float M = wmax64(m);
  float S = wsum64(s * expf(m - M));
  float rd = 1.f / (S + 1e-16f);

  // pass B: 16-lane quarters, weights from LDS
  int q = l >> 4;             // 0..3
  int c4 = (l & 15) * 4;      // 4 channels per lane
  float a0 = 0.f, a1 = 0.f, a2 = 0.f, a3 = 0.f;
  for (int cs = beg; cs < end; cs += 64){
    int cn = min(64, end - cs);
    __syncthreads();
    if (l < cn){
      int sj = csrc[cs + l];
      s_src[l] = sj;
      s_w[l] = expf(lrelu(as2[sj] + adv) - M) * rd;
    }
    __syncthreads();
    for (int e = q; e < cn; e += 4){
      int src = s_src[e];
      float w = s_w[e];
      ushort4 u = *(const ushort4*)(h2b + (size_t)src*OUT_CH + c4);
      a0 += w * b2f(u.x);
      a1 += w * b2f(u.y);
      a2 += w * b2f(u.z);
      a3 += w * b2f(u.w);
    }
  }
  a0 += __shfl_xor(a0, 32, 64); a0 += __shfl_xor(a0, 16, 64);
  a1 += __shfl_xor(a1, 32, 64); a1 += __shfl_xor(a1, 16, 64);
  a2 += __shfl_xor(a2, 32, 64); a2 += __shfl_xor(a2, 16, 64);
  a3 += __shfl_xor(a3, 32, 64); a3 += __shfl_xor(a3, 16, 64);
  if (q == 0){
    ushort4 o;
    o.x = f2b(a0 + bias[c4]);
    o.y = f2b(a1 + bias[c4+1]);
    o.z = f2b(a2 + bias[c4+2]);
    o.w = f2b(a3 + bias[c4+3]);
    *(ushort4*)(z2b + (size_t)i*OUT_CH + c4) = o;
  }
}

// ---------------- bf16 MFMA GEMM, BM=128, BN=64, BK=64, strided, batched-z ----
template<bool RELU_BIAS>
__global__ __launch_bounds__(256) void k_gemm2(
    const ushort* __restrict__ A, const ushort* __restrict__ Bt,
    ushort* __restrict__ Cb, const float* __restrict__ bias,
    int M, int K, int lda, int ldc, int aZ, int bZ, int cZ)
{
  constexpr int BM = 128, BN = 64, NF = 2;
  __shared__ uint4 As[BM*8];
  __shared__ uint4 Bs[BN*8];
  int tid = threadIdx.x;
  int wave = tid >> 6, lane = tid & 63;
  int wr = wave >> 1, wc = wave & 1;
  int bm = blockIdx.y * BM;
  int z = blockIdx.z;
  const ushort* Az = A + (size_t)z*aZ;
  const ushort* Bz = Bt + (size_t)z*bZ;
  int g = lane >> 4, lr = lane & 15;

  f32x4 acc[4][NF];
  #pragma unroll
  for (int m = 0; m < 4; ++m)
    #pragma unroll
    for (int n = 0; n < NF; ++n) acc[m][n] = (f32x4)(0.f);

  for (int k0 = 0; k0 < K; k0 += 64){
    for (int idx = tid; idx < BM*8; idx += 256){
      int r = idx >> 3, c = idx & 7;
      int gr = bm + r;
      uint4 v = make_uint4(0u,0u,0u,0u);
      if (gr < M) v = *(const uint4*)(Az + (size_t)gr*lda + k0 + c*8);
      As[r*8 + (c ^ (r & 7))] = v;
    }
    for (int idx = tid; idx < BN*8; idx += 256){
      int r = idx >> 3, c = idx & 7;
      uint4 v = *(const uint4*)(Bz + (size_t)r*K + k0 + c*8);
      Bs[r*8 + (c ^ (r & 7))] = v;
    }
    __syncthreads();
    #pragma unroll
    for (int kk = 0; kk < 2; ++kk){
      short8v af[4], bf[NF];
      #pragma unroll
      for (int m = 0; m < 4; ++m){
        int r = wr*64 + m*16 + lr;
        int c = kk*4 + g;
        af[m] = *(const short8v*)&As[r*8 + (c ^ (r & 7))];
      }
      #pragma unroll
      for (int n = 0; n < NF; ++n){
        int r = wc*32 + n*16 + lr;
        int c = kk*4 + g;
        bf[n] = *(const short8v*)&Bs[r*8 + (c ^ (r & 7))];
      }
      #pragma unroll
      for (int m = 0; m < 4; ++m)
        #pragma unroll
        for (int n = 0; n < NF; ++n)
          acc[m][n] = __builtin_amdgcn_mfma_f32_16x16x32_bf16(af[m], bf[n], acc[m][n], 0, 0, 0);
    }
    __syncthreads();
  }
  #pragma unroll
  for (int m = 0; m < 4; ++m){
    #pragma unroll
    for (int q = 0; q < 4; ++q){
      int row = bm + wr*64 + m*16 + g*4 + q;
      if (row < M){
        #pragma unroll
        for (int n = 0; n < NF; ++n){
          int col = wc*32 + n*16 + lr;
          float v = acc[m][n][q];
          if (RELU_BIAS) v = fmaxf(v + bias[cZ*z + col], 0.f);
          Cb[(size_t)row*ldc + cZ*z + col] = f2b(v);
        }
      }
    }
  }
}

// ---------------- decoder: 2 edges (pos[k], neg[k]) per 8-lane group ----------
__global__ void k_decode(const ushort* __restrict__ z2b, const int* __restrict__ pos,
                         const int* __restrict__ neg, float* __restrict__ out, int e){
  int g = blockIdx.x*256 + threadIdx.x;
  int k = g >> 3;
  int sub = g & 7;
  if (k >= e) return;
  int a0 = __builtin_nontemporal_load(pos + k);
  int b0 = __builtin_nontemporal_load(pos + e + k);
  int a1 = __builtin_nontemporal_load(neg + k);
  int b1 = __builtin_nontemporal_load(neg + e + k);
  uint4 ua0 = *(const uint4*)(z2b + (size_t)a0*OUT_CH + sub*8);
  uint4 ub0 = *(const uint4*)(z2b + (size_t)b0*OUT_CH + sub*8);
  uint4 ua1 = *(const uint4*)(z2b + (size_t)a1*OUT_CH + sub*8);
  uint4 ub1 = *(const uint4*)(z2b + (size_t)b1*OUT_CH + sub*8);
  float p0 = dot2(ua0.x, ub0.x) + dot2(ua0.y, ub0.y) + dot2(ua0.z, ub0.z) + dot2(ua0.w, ub0.w);
  float p1 = dot2(ua1.x, ub1.x) + dot2(ua1.y, ub1.y) + dot2(ua1.z, ub1.z) + dot2(ua1.w, ub1.w);
  p0 += __shfl_xor(p0, 4, 64); p1 += __shfl_xor(p1, 4, 64);
  p0 += __shfl_xor(p0, 2, 64); p1 += __shfl_xor(p1, 2, 64);
  p0 += __shfl_xor(p0, 1, 64); p1 += __shfl_xor(p1, 1, 64);
  if (sub == 0){
    __builtin_nontemporal_store(p0, out + k);
    __builtin_nontemporal_store(p1, out + e + k);
  }
}

extern "C" void kernel_launch(void* const* d_in, const int* in_sizes, int n_in,
                              void* d_out, int out_size, void* d_ws, size_t ws_size,
                              hipStream_t stream) {
  const float* x        = (const float*)d_in[0];
  const int*   pos      = (const int*)d_in[1];
  const int*   neg      = (const int*)d_in[2];
  const float* W1       = (const float*)d_in[3];
  const float* att_src1 = (const float*)d_in[4];
  const float* att_dst1 = (const float*)d_in[5];
  const float* b1       = (const float*)d_in[6];
  const float* W2       = (const float*)d_in[7];
  const float* att_src2 = (const float*)d_in[8];
  const float* att_dst2 = (const float*)d_in[9];
  const float* b2       = (const float*)d_in[10];
  float* out = (float*)d_out;

  const int N = in_sizes[0] / IN_CH;   // 50000
  const int E = in_sizes[1] / 2;       // 800000
  const int NNZ = E + N;               // edges + self-loops

  char* w = (char*)d_ws;
  ushort* xb   = (ushort*)w;  w += (size_t)N*IN_CH*2;
  ushort* xagg = (ushort*)w;  w += (size_t)N*512*2;          // 51.2MB; sub-reused below
  ushort* z1b  = (ushort*)w;  w += (size_t)N*C1*2;
  float* as1   = (float*)w;   w += (size_t)N*4*4;
  float* ad1   = (float*)w;   w += (size_t)N*4*4;
  float* as2   = (float*)w;   w += (size_t)N*4;
  float* ad2   = (float*)w;   w += (size_t)N*4;
  ushort* W1t  = (ushort*)w;  w += (size_t)C1*IN_CH*2;
  ushort* W2t  = (ushort*)w;  w += (size_t)OUT_CH*C1*2;
  float* was4  = (float*)w;   w += 512*4;
  float* wad4  = (float*)w;   w += 512*4;
  float* w2s   = (float*)w;   w += 256*4;
  float* w2d   = (float*)w;   w += 256*4;
  int* deg     = (int*)w;     w += (size_t)N*4;
  int* rowptr  = (int*)w;     w += (size_t)(N+1)*4;
  int* cursor  = (int*)w;     w += (size_t)N*4;
  int* bsum    = (int*)w;     w += (size_t)256*4;
  int* csrc    = (int*)w;     w += (size_t)NNZ*4;

  // sub-allocations inside xagg (region dead after z1 GEMM):
  ushort* h2b = xagg;                                  // 6.4MB
  ushort* z2b = xagg + (size_t)N*OUT_CH;               // 6.4MB

  int eb = (E + 255)/256;
  int nb = (N + 255)/256;
  const int* pdst = pos + E;

  k_init<<<nb, 256, 0, stream>>>(deg, N);
  k_hist<<<eb, 256, 0, stream>>>(pdst, deg, E);
  k_blocksum<<<nb, 256, 0, stream>>>(deg, bsum, N);
  k_scanb<<<1, 256, 0, stream>>>(bsum, nb);
  k_scanfinal<<<nb, 256, 0, stream>>>(deg, bsum, rowptr, cursor, csrc, N);
  k_scatter<<<eb, 256, 0, stream>>>(pos, pdst, cursor, csrc, E);

  k_tw<<<(IN_CH*C1 + 255)/256, 256, 0, stream>>>(W1, W1t, IN_CH, C1);
  k_tw<<<(C1*OUT_CH + 255)/256, 256, 0, stream>>>(W2, W2t, C1, OUT_CH);
  k_folds<<<2, 512, 0, stream>>>(W1, att_src1, att_dst1, W2, att_src2, att_dst2,
                                 was4, wad4, w2s, w2d);

  k_fattc<<<N, 64, 0, stream>>>(x, was4, wad4, xb, as1, ad1, N);
  k_fagg1<<<N, 64, 0, stream>>>(xb, as1, ad1, rowptr, csrc, xagg, N);

  {  // z1 = relu(blockdiag(xagg_h @ W1_h) + b1), 4 heads via blockIdx.z
    dim3 g(1, (N + 127)/128, 4);
    k_gemm2<true><<<g, 256, 0, stream>>>(xagg, W1t, z1b, b1,
        N, IN_CH, 512, C1, IN_CH, OUT_CH*IN_CH, OUT_CH);
  }
  k_fatt2<<<N, 64, 0, stream>>>(z1b, w2s, w2d, as2, ad2, N);

  {  // h2 = z1 @ W2
    dim3 g(1, (N + 127)/128, 1);
    k_gemm2<false><<<g, 256, 0, stream>>>(z1b, W2t, h2b, nullptr,
        N, C1, C1, OUT_CH, 0, 0, 0);
  }
  k_fagg2<<<N, 64, 0, stream>>>(h2b, as2, ad2, rowptr, csrc, b2, z2b, N);

  int db = (int)(((size_t)E*8 + 255)/256);
  k_decode<<<db, 256, 0, stream>>>(z2b, pos, neg, out, E);
}